// Round 1
// baseline (754.170 us; speedup 1.0000x reference)
//
#include <hip/hip_runtime.h>
#include <hip/hip_bf16.h>

#define DM 1024
#define NH 16
#define AD 64
#define BB 2
#define SS 2048

typedef float f32x4 __attribute__((ext_vector_type(4)));
typedef short bf16x8 __attribute__((ext_vector_type(8)));
typedef unsigned short u16;
typedef u16 u16x4 __attribute__((ext_vector_type(4)));
typedef u16 u16x8 __attribute__((ext_vector_type(8)));

static __device__ __forceinline__ u16 f2bf(float f) {
  unsigned u = __builtin_bit_cast(unsigned, f);
  u += 0x7fffu + ((u >> 16) & 1u);  // round-to-nearest-even
  return (u16)(u >> 16);
}

#define MFMA16(a, b, c) __builtin_amdgcn_mfma_f32_16x16x32_bf16((a), (b), (c), 0, 0, 0)

// ---------------- fp32 -> bf16 cast, 8 elems/thread ----------------
__global__ __launch_bounds__(256, 4) void cast_bf16_kernel(const float* __restrict__ src,
                                                           u16* __restrict__ dst, int n8) {
  int i = blockIdx.x * blockDim.x + threadIdx.x;
  int stride = gridDim.x * blockDim.x;
  for (; i < n8; i += stride) {
    const f32x4* p = (const f32x4*)src + 2 * (size_t)i;
    f32x4 a = p[0], b = p[1];
    u16x8 o;
    o[0] = f2bf(a[0]); o[1] = f2bf(a[1]); o[2] = f2bf(a[2]); o[3] = f2bf(a[3]);
    o[4] = f2bf(b[0]); o[5] = f2bf(b[1]); o[6] = f2bf(b[2]); o[7] = f2bf(b[3]);
    *((u16x8*)dst + i) = o;
  }
}

// ---------------- transpose + cast: src[R][C] f32 -> dst[C][R] bf16 (batched on z) ----------------
__global__ __launch_bounds__(256, 4) void tcast_kernel(const float* __restrict__ src,
                                                       u16* __restrict__ dst, int R, int C,
                                                       float scale) {
  long bo = (long)blockIdx.z * R * C;
  int t = blockIdx.x * 256 + threadIdx.x;
  if (t >= R * C) return;
  int c = t / R, r = t - c * R;
  dst[bo + t] = f2bf(src[bo + (long)r * C + c] * scale);
}

// ---------------- projection GEMM: C[s, e] = sum_k X[b][s][k] * WT[h*64+e][k] ----------------
// block: 256 thr (4 waves), tile 64 s-rows x 64 cols; wave w owns col-tile et=w; 4 m-subtiles.
// MODE 0: bf16 out at b*ob + h*oh + s*os + e*oe
// MODE 1: bf16 out transposed: b*ob + h*oh + e*oe + s   (4 consecutive s packed)
// MODE 2: f32 out at b*ob + h*oh + s*os + e*oe
template <int MODE>
__global__ __launch_bounds__(256, 4) void proj_kernel(const u16* __restrict__ X,
                                                      const u16* __restrict__ WT,
                                                      void* __restrict__ outp, long ob, long oh,
                                                      long os, long oe) {
  int s0 = blockIdx.x * 64;
  int h = blockIdx.y;
  int b = blockIdx.z;
  int tid = threadIdx.x;
  int w = tid >> 6, lane = tid & 63;
  int g = lane >> 4, li = lane & 15;
  const u16* xb = X + ((long)b * SS + s0) * DM;
  const u16* wb = WT + ((long)(h * 64 + w * 16 + li)) * DM;
  f32x4 acc[4] = {};
  for (int k0 = 0; k0 < DM; k0 += 32) {
    bf16x8 bfrag = *(const bf16x8*)(wb + k0 + 8 * g);
#pragma unroll
    for (int mi = 0; mi < 4; mi++) {
      bf16x8 afrag = *(const bf16x8*)(xb + (long)(mi * 16 + li) * DM + k0 + 8 * g);
      acc[mi] = MFMA16(afrag, bfrag, acc[mi]);
    }
  }
  int e = w * 16 + li;
  long bh = (long)b * ob + (long)h * oh;
#pragma unroll
  for (int mi = 0; mi < 4; mi++) {
    int sb = s0 + mi * 16 + 4 * g;  // D row = (lane>>4)*4 + reg
    if (MODE == 0) {
      u16* o = (u16*)outp;
#pragma unroll
      for (int r = 0; r < 4; r++) o[bh + (long)(sb + r) * os + (long)e * oe] = f2bf(acc[mi][r]);
    } else if (MODE == 1) {
      u16x4 v;
#pragma unroll
      for (int r = 0; r < 4; r++) v[r] = f2bf(acc[mi][r]);
      *(u16x4*)((u16*)outp + bh + (long)e * oe + sb) = v;
    } else {
      float* o = (float*)outp;
#pragma unroll
      for (int r = 0; r < 4; r++) o[bh + (long)(sb + r) * os + (long)e * oe] = acc[mi][r];
    }
  }
}

// ---------------- fused attention: scores^T + softmax + attn write + PV + cat ----------------
// block: 512 thr (8 waves), one (h, b, 16-q-row tile). Wave w owns k-range [w*256, w*256+256).
// S^T = kh @ qh^T  (A = kh rows -> m = k, B = qh^T -> n = q) so lane (g,li) holds
// S^T[k = w*256 + ct*16 + 4g + r][q = q0 + li]: one q-row per lane along k.
__global__ __launch_bounds__(512, 1) void attn_kernel(const u16* __restrict__ qh,
                                                      const u16* __restrict__ kh,
                                                      const u16* __restrict__ vhT,
                                                      float* __restrict__ attn_out,
                                                      u16* __restrict__ cat) {
  __shared__ u16 P[8][16][264];     // per-wave P tile [q=16][k=256], +8 pad -> 2-way banks
  __shared__ float redm[8][16];
  __shared__ float redl[8][16];
  __shared__ float reda[8][16][64]; // per-wave partial att
  int q0 = blockIdx.x * 16;
  int h = blockIdx.y, b = blockIdx.z;
  int hb = h * BB + b;
  int tid = threadIdx.x;
  int w = tid >> 6, lane = tid & 63;
  int g = lane >> 4, li = lane & 15;
  long base = (long)hb * SS * AD;
  const u16* qhb = qh + base;
  const u16* khb = kh + base;
  const u16* vhb = vhT + base;

  bf16x8 bq0 = *(const bf16x8*)(qhb + (q0 + li) * AD + 8 * g);
  bf16x8 bq1 = *(const bf16x8*)(qhb + (q0 + li) * AD + 32 + 8 * g);

  f32x4 acc[16];
#pragma unroll
  for (int ct = 0; ct < 16; ct++) {
    int krow = w * 256 + ct * 16 + li;
    bf16x8 ak0 = *(const bf16x8*)(khb + (long)krow * AD + 8 * g);
    bf16x8 ak1 = *(const bf16x8*)(khb + (long)krow * AD + 32 + 8 * g);
    f32x4 c = {};
    c = MFMA16(ak0, bq0, c);
    c = MFMA16(ak1, bq1, c);
    acc[ct] = c;
  }

  // ---- row max over k (scores already include the 1/64, folded into WqT) ----
  float m = -3.0e38f;
#pragma unroll
  for (int ct = 0; ct < 16; ct++)
#pragma unroll
    for (int r = 0; r < 4; r++) m = fmaxf(m, acc[ct][r]);
  m = fmaxf(m, __shfl_xor(m, 16));
  m = fmaxf(m, __shfl_xor(m, 32));
  if (lane < 16) redm[w][li] = m;
  __syncthreads();
#pragma unroll
  for (int w2 = 0; w2 < 8; w2++) m = fmaxf(m, redm[w2][li]);

  // ---- exp + row sum ----
  float l = 0.f;
#pragma unroll
  for (int ct = 0; ct < 16; ct++)
#pragma unroll
    for (int r = 0; r < 4; r++) {
      float p = exp2f((acc[ct][r] - m) * 1.44269504f);
      acc[ct][r] = p;
      l += p;
    }
  l += __shfl_xor(l, 16);
  l += __shfl_xor(l, 32);
  if (lane < 16) redl[w][li] = l;
  __syncthreads();
  l = 0.f;
#pragma unroll
  for (int w2 = 0; w2 < 8; w2++) l += redl[w2][li];
  float rinv = 1.0f / l;

  // ---- write normalized attn (fp32, float4) + stash bf16 P in LDS ----
  float* arow = attn_out + ((long)(hb * SS + q0 + li)) * SS + w * 256;
#pragma unroll
  for (int ct = 0; ct < 16; ct++) {
    f32x4 vv;
#pragma unroll
    for (int r = 0; r < 4; r++) vv[r] = acc[ct][r] * rinv;
    *(f32x4*)(arow + ct * 16 + 4 * g) = vv;
    u16x4 pv;
#pragma unroll
    for (int r = 0; r < 4; r++) pv[r] = f2bf(vv[r]);
    *(u16x4*)(&P[w][li][ct * 16 + 4 * g]) = pv;
  }
  __syncthreads();

  // ---- PV: att_part[q, e] over this wave's 256 k ----
  f32x4 accv[4] = {};
#pragma unroll
  for (int s8 = 0; s8 < 8; s8++) {
    bf16x8 ap = *(const bf16x8*)(&P[w][li][s8 * 32 + 8 * g]);  // A = P[q=li][k]
#pragma unroll
    for (int et = 0; et < 4; et++) {
      bf16x8 bv = *(const bf16x8*)(vhb + (long)(et * 16 + li) * SS + w * 256 + s8 * 32 + 8 * g);
      accv[et] = MFMA16(ap, bv, accv[et]);
    }
  }

  // ---- cross-wave reduction of att, then emit bf16 cat ----
#pragma unroll
  for (int et = 0; et < 4; et++)
#pragma unroll
    for (int r = 0; r < 4; r++) reda[w][4 * g + r][et * 16 + li] = accv[et][r];
  __syncthreads();
  int qq = tid >> 5;   // 0..15
  int ep = tid & 31;   // e = 2*ep, 2*ep+1
  float s0v = 0.f, s1v = 0.f;
#pragma unroll
  for (int w2 = 0; w2 < 8; w2++) {
    s0v += reda[w2][qq][2 * ep];
    s1v += reda[w2][qq][2 * ep + 1];
  }
  unsigned pk = (unsigned)f2bf(s0v) | ((unsigned)f2bf(s1v) << 16);
  *(unsigned*)(cat + ((long)b * SS + q0 + qq) * DM + h * AD + 2 * ep) = pk;
}

extern "C" void kernel_launch(void* const* d_in, const int* in_sizes, int n_in, void* d_out,
                              int out_size, void* d_ws, size_t ws_size, hipStream_t stream) {
  const float* q = (const float*)d_in[0];
  const float* k = (const float*)d_in[1];
  const float* v = (const float*)d_in[2];
  const float* Wq = (const float*)d_in[3];
  const float* Wk = (const float*)d_in[4];
  const float* Wv = (const float*)d_in[5];
  const float* Wo = (const float*)d_in[6];
  float* out = (float*)d_out;
  float* attn_out = out + (long)BB * SS * DM;

  const long NX = (long)BB * SS * DM;  // 4,194,304
  const long NW = (long)NH * DM * AD;  // 1,048,576
  u16* ws = (u16*)d_ws;
  u16* xq = ws;
  u16* xk = xq + NX;
  u16* xv = xk + NX;
  u16* WqT = xv + NX;
  u16* WkT = WqT + NW;
  u16* WvT = WkT + NW;
  u16* WoT = WvT + NW;
  u16* qhw = WoT + (long)DM * DM;
  u16* khw = qhw + NX;
  u16* vhw = khw + NX;
  u16* catw = vhw + NX;  // total ws use: 64 MiB

  cast_bf16_kernel<<<2048, 256, 0, stream>>>(q, xq, (int)(NX / 8));
  cast_bf16_kernel<<<2048, 256, 0, stream>>>(k, xk, (int)(NX / 8));
  cast_bf16_kernel<<<2048, 256, 0, stream>>>(v, xv, (int)(NX / 8));
  // fold 1/ATT_DIM into WqT: exact (2^-6)
  tcast_kernel<<<dim3(256, 1, NH), 256, 0, stream>>>(Wq, WqT, DM, AD, 1.0f / AD);
  tcast_kernel<<<dim3(256, 1, NH), 256, 0, stream>>>(Wk, WkT, DM, AD, 1.0f);
  tcast_kernel<<<dim3(256, 1, NH), 256, 0, stream>>>(Wv, WvT, DM, AD, 1.0f);
  tcast_kernel<<<dim3(4096, 1, 1), 256, 0, stream>>>(Wo, WoT, DM, DM, 1.0f);

  dim3 pg(SS / 64, NH, BB);
  // qh[h][b][s][e], kh[h][b][s][e]
  proj_kernel<0><<<pg, 256, 0, stream>>>(xq, WqT, qhw, (long)SS * AD, (long)BB * SS * AD, AD, 1);
  proj_kernel<0><<<pg, 256, 0, stream>>>(xk, WkT, khw, (long)SS * AD, (long)BB * SS * AD, AD, 1);
  // vhT[h][b][e][s]
  proj_kernel<1><<<pg, 256, 0, stream>>>(xv, WvT, vhw, (long)SS * AD, (long)BB * SS * AD, 1, SS);

  attn_kernel<<<dim3(SS / 16, NH, BB), 512, 0, stream>>>(qhw, khw, vhw, attn_out, catw);

  // out[b][s][d] = cat @ Wo
  proj_kernel<2><<<pg, 256, 0, stream>>>(catw, WoT, out, (long)SS * DM, AD, DM, 1);
}

// Round 2
// 688.818 us; speedup vs baseline: 1.0949x; 1.0949x over previous
//
#include <hip/hip_runtime.h>
#include <hip/hip_bf16.h>

#define DM 1024
#define NH 16
#define AD 64
#define BB 2
#define SS 2048

typedef float f32x4 __attribute__((ext_vector_type(4)));
typedef short bf16x8 __attribute__((ext_vector_type(8)));
typedef unsigned short u16;
typedef u16 u16x4 __attribute__((ext_vector_type(4)));
typedef u16 u16x8 __attribute__((ext_vector_type(8)));

static __device__ __forceinline__ u16 f2bf(float f) {
  unsigned u = __builtin_bit_cast(unsigned, f);
  u += 0x7fffu + ((u >> 16) & 1u);  // round-to-nearest-even
  return (u16)(u >> 16);
}

#define MFMA16(a, b, c) __builtin_amdgcn_mfma_f32_16x16x32_bf16((a), (b), (c), 0, 0, 0)

// ---------------- fp32 -> bf16 cast, 8 elems/thread ----------------
__global__ __launch_bounds__(256, 4) void cast_bf16_kernel(const float* __restrict__ src,
                                                           u16* __restrict__ dst, int n8) {
  int i = blockIdx.x * blockDim.x + threadIdx.x;
  int stride = gridDim.x * blockDim.x;
  for (; i < n8; i += stride) {
    const f32x4* p = (const f32x4*)src + 2 * (size_t)i;
    f32x4 a = p[0], b = p[1];
    u16x8 o;
    o[0] = f2bf(a[0]); o[1] = f2bf(a[1]); o[2] = f2bf(a[2]); o[3] = f2bf(a[3]);
    o[4] = f2bf(b[0]); o[5] = f2bf(b[1]); o[6] = f2bf(b[2]); o[7] = f2bf(b[3]);
    *((u16x8*)dst + i) = o;
  }
}

// ---------------- transpose + cast: src[R][C] f32 -> dst[C][R] bf16 (batched on z) ----------------
__global__ __launch_bounds__(256, 4) void tcast_kernel(const float* __restrict__ src,
                                                       u16* __restrict__ dst, int R, int C,
                                                       float scale) {
  long bo = (long)blockIdx.z * R * C;
  int t = blockIdx.x * 256 + threadIdx.x;
  if (t >= R * C) return;
  int c = t / R, r = t - c * R;
  dst[bo + t] = f2bf(src[bo + (long)r * C + c] * scale);
}

// ---------------- projection GEMM: C[s, e] = sum_k X[b][s][k] * WT[h*64+e][k] ----------------
// block: 256 thr (4 waves), tile 64 s-rows x 64 cols; wave w owns col-tile et=w; 4 m-subtiles.
// MODE 0: bf16 out at b*ob + h*oh + s*os + e*oe
// MODE 1: bf16 out transposed: b*ob + h*oh + e*oe + s   (4 consecutive s packed)
// MODE 2: f32 out at b*ob + h*oh + s*os + e*oe
template <int MODE>
__global__ __launch_bounds__(256, 4) void proj_kernel(const u16* __restrict__ X,
                                                      const u16* __restrict__ WT,
                                                      void* __restrict__ outp, long ob, long oh,
                                                      long os, long oe) {
  int s0 = blockIdx.x * 64;
  int h = blockIdx.y;
  int b = blockIdx.z;
  int tid = threadIdx.x;
  int w = tid >> 6, lane = tid & 63;
  int g = lane >> 4, li = lane & 15;
  const u16* xb = X + ((long)b * SS + s0) * DM;
  const u16* wb = WT + ((long)(h * 64 + w * 16 + li)) * DM;
  f32x4 acc[4] = {};
  for (int k0 = 0; k0 < DM; k0 += 32) {
    bf16x8 bfrag = *(const bf16x8*)(wb + k0 + 8 * g);
#pragma unroll
    for (int mi = 0; mi < 4; mi++) {
      bf16x8 afrag = *(const bf16x8*)(xb + (long)(mi * 16 + li) * DM + k0 + 8 * g);
      acc[mi] = MFMA16(afrag, bfrag, acc[mi]);
    }
  }
  int e = w * 16 + li;
  long bh = (long)b * ob + (long)h * oh;
#pragma unroll
  for (int mi = 0; mi < 4; mi++) {
    int sb = s0 + mi * 16 + 4 * g;  // D row = (lane>>4)*4 + reg
    if (MODE == 0) {
      u16* o = (u16*)outp;
#pragma unroll
      for (int r = 0; r < 4; r++) o[bh + (long)(sb + r) * os + (long)e * oe] = f2bf(acc[mi][r]);
    } else if (MODE == 1) {
      u16x4 v;
#pragma unroll
      for (int r = 0; r < 4; r++) v[r] = f2bf(acc[mi][r]);
      *(u16x4*)((u16*)outp + bh + (long)e * oe + sb) = v;
    } else {
      float* o = (float*)outp;
#pragma unroll
      for (int r = 0; r < 4; r++) o[bh + (long)(sb + r) * os + (long)e * oe] = acc[mi][r];
    }
  }
}

// ---------------- fused attention: scores^T + softmax + attn write + PV + cat ----------------
// block: 512 thr (8 waves), one (h, b, 16-q-row tile). Wave w owns k-range [w*256, w*256+256).
// S^T = kh @ qh^T  (A = kh rows -> m = k, B = qh^T -> n = q) so lane (g,li) holds
// S^T[k = w*256 + ct*16 + 4g + r][q = q0 + li]: one q-row per lane along k.
// LDS budget 68.6KB -> 2 blocks/CU. reda aliases each wave's own P slice (written by w,
// read by w for PV, then overwritten by w after its own PV reads; same-wave DS is ordered).
__global__ __launch_bounds__(512, 4) void attn_kernel(const u16* __restrict__ qh,
                                                      const u16* __restrict__ kh,
                                                      const u16* __restrict__ vhT,
                                                      float* __restrict__ attn_out,
                                                      u16* __restrict__ cat) {
  __shared__ u16 P[8][16][264];  // per-wave P tile [q=16][k=256], padded
  __shared__ float redm[8][16];
  __shared__ float redl[8][16];
  int q0 = blockIdx.x * 16;
  int h = blockIdx.y, b = blockIdx.z;
  int hb = h * BB + b;
  int tid = threadIdx.x;
  int w = tid >> 6, lane = tid & 63;
  int g = lane >> 4, li = lane & 15;
  long base = (long)hb * SS * AD;
  const u16* qhb = qh + base;
  const u16* khb = kh + base;
  const u16* vhb = vhT + base;

  bf16x8 bq0 = *(const bf16x8*)(qhb + (q0 + li) * AD + 8 * g);
  bf16x8 bq1 = *(const bf16x8*)(qhb + (q0 + li) * AD + 32 + 8 * g);

  f32x4 acc[16];
#pragma unroll
  for (int ct = 0; ct < 16; ct++) {
    int krow = w * 256 + ct * 16 + li;
    bf16x8 ak0 = *(const bf16x8*)(khb + (long)krow * AD + 8 * g);
    bf16x8 ak1 = *(const bf16x8*)(khb + (long)krow * AD + 32 + 8 * g);
    f32x4 c = {};
    c = MFMA16(ak0, bq0, c);
    c = MFMA16(ak1, bq1, c);
    acc[ct] = c;
  }

  // ---- per-wave row max over this wave's 256 k (1/64 scale folded into WqT) ----
  float mw = -3.0e38f;
#pragma unroll
  for (int ct = 0; ct < 16; ct++)
#pragma unroll
    for (int r = 0; r < 4; r++) mw = fmaxf(mw, acc[ct][r]);
  mw = fmaxf(mw, __shfl_xor(mw, 16));
  mw = fmaxf(mw, __shfl_xor(mw, 32));

  // ---- per-wave exp + partial sum (deferred rescale) ----
  float lw = 0.f;
#pragma unroll
  for (int ct = 0; ct < 16; ct++)
#pragma unroll
    for (int r = 0; r < 4; r++) {
      float p = exp2f((acc[ct][r] - mw) * 1.44269504f);
      acc[ct][r] = p;
      lw += p;
    }
  lw += __shfl_xor(lw, 16);
  lw += __shfl_xor(lw, 32);
  if (lane < 16) {
    redm[w][li] = mw;
    redl[w][li] = lw;
  }
  __syncthreads();  // the ONLY softmax barrier

  // ---- merge: global max + rescaled sum ----
  float m = -3.0e38f;
#pragma unroll
  for (int w2 = 0; w2 < 8; w2++) m = fmaxf(m, redm[w2][li]);
  float l = 0.f;
#pragma unroll
  for (int w2 = 0; w2 < 8; w2++)
    l += redl[w2][li] * exp2f((redm[w2][li] - m) * 1.44269504f);
  float fscale = exp2f((mw - m) * 1.44269504f) / l;

  // ---- write normalized attn (fp32, float4) + stash bf16 P in own LDS slice ----
  float* arow = attn_out + ((long)(hb * SS + q0 + li)) * SS + w * 256;
#pragma unroll
  for (int ct = 0; ct < 16; ct++) {
    f32x4 vv;
#pragma unroll
    for (int r = 0; r < 4; r++) vv[r] = acc[ct][r] * fscale;
    *(f32x4*)(arow + ct * 16 + 4 * g) = vv;
    u16x4 pv;
#pragma unroll
    for (int r = 0; r < 4; r++) pv[r] = f2bf(vv[r]);
    *(u16x4*)(&P[w][li][ct * 16 + 4 * g]) = pv;
  }
  // P[w] written and read only by wave w: intra-wave DS ordering suffices (no barrier)
  asm volatile("s_waitcnt lgkmcnt(0)" ::: "memory");

  // ---- PV: att_part[q, e] over this wave's 256 k ----
  f32x4 accv[4] = {};
#pragma unroll
  for (int s8 = 0; s8 < 8; s8++) {
    bf16x8 ap = *(const bf16x8*)(&P[w][li][s8 * 32 + 8 * g]);  // A = P[q=li][k]
#pragma unroll
    for (int et = 0; et < 4; et++) {
      bf16x8 bv = *(const bf16x8*)(vhb + (long)(et * 16 + li) * SS + w * 256 + s8 * 32 + 8 * g);
      accv[et] = MFMA16(ap, bv, accv[et]);
    }
  }

  // ---- cross-wave reduction of att: reda aliases wave's OWN P slice ----
  float* reda = (float*)&P[w][0][0];  // 16 rows x 69 floats = 4416B <= 8448B slice
#pragma unroll
  for (int et = 0; et < 4; et++)
#pragma unroll
    for (int r = 0; r < 4; r++) reda[(4 * g + r) * 69 + et * 16 + li] = accv[et][r];
  __syncthreads();
  int qq = tid >> 5;  // 0..15
  int ep = tid & 31;  // e = 2*ep, 2*ep+1
  float s0v = 0.f, s1v = 0.f;
#pragma unroll
  for (int w2 = 0; w2 < 8; w2++) {
    const float* rw = (const float*)&P[w2][0][0];
    s0v += rw[qq * 69 + 2 * ep];
    s1v += rw[qq * 69 + 2 * ep + 1];
  }
  unsigned pk = (unsigned)f2bf(s0v) | ((unsigned)f2bf(s1v) << 16);
  *(unsigned*)(cat + ((long)b * SS + q0 + qq) * DM + h * AD + 2 * ep) = pk;
}

extern "C" void kernel_launch(void* const* d_in, const int* in_sizes, int n_in, void* d_out,
                              int out_size, void* d_ws, size_t ws_size, hipStream_t stream) {
  const float* q = (const float*)d_in[0];
  const float* k = (const float*)d_in[1];
  const float* v = (const float*)d_in[2];
  const float* Wq = (const float*)d_in[3];
  const float* Wk = (const float*)d_in[4];
  const float* Wv = (const float*)d_in[5];
  const float* Wo = (const float*)d_in[6];
  float* out = (float*)d_out;
  float* attn_out = out + (long)BB * SS * DM;

  const long NX = (long)BB * SS * DM;  // 4,194,304
  const long NW = (long)NH * DM * AD;  // 1,048,576
  u16* ws = (u16*)d_ws;
  u16* xq = ws;
  u16* xk = xq + NX;
  u16* xv = xk + NX;
  u16* WqT = xv + NX;
  u16* WkT = WqT + NW;
  u16* WvT = WkT + NW;
  u16* WoT = WvT + NW;
  u16* qhw = WoT + (long)DM * DM;
  u16* khw = qhw + NX;
  u16* vhw = khw + NX;
  u16* catw = vhw + NX;  // total ws use: 64 MiB

  cast_bf16_kernel<<<2048, 256, 0, stream>>>(q, xq, (int)(NX / 8));
  cast_bf16_kernel<<<2048, 256, 0, stream>>>(k, xk, (int)(NX / 8));
  cast_bf16_kernel<<<2048, 256, 0, stream>>>(v, xv, (int)(NX / 8));
  // fold 1/ATT_DIM into WqT: exact (2^-6)
  tcast_kernel<<<dim3(256, 1, NH), 256, 0, stream>>>(Wq, WqT, DM, AD, 1.0f / AD);
  tcast_kernel<<<dim3(256, 1, NH), 256, 0, stream>>>(Wk, WkT, DM, AD, 1.0f);
  tcast_kernel<<<dim3(256, 1, NH), 256, 0, stream>>>(Wv, WvT, DM, AD, 1.0f);
  tcast_kernel<<<dim3(4096, 1, 1), 256, 0, stream>>>(Wo, WoT, DM, DM, 1.0f);

  dim3 pg(SS / 64, NH, BB);
  // qh[h][b][s][e], kh[h][b][s][e]
  proj_kernel<0><<<pg, 256, 0, stream>>>(xq, WqT, qhw, (long)SS * AD, (long)BB * SS * AD, AD, 1);
  proj_kernel<0><<<pg, 256, 0, stream>>>(xk, WkT, khw, (long)SS * AD, (long)BB * SS * AD, AD, 1);
  // vhT[h][b][e][s]
  proj_kernel<1><<<pg, 256, 0, stream>>>(xv, WvT, vhw, (long)SS * AD, (long)BB * SS * AD, 1, SS);

  attn_kernel<<<dim3(SS / 16, NH, BB), 512, 0, stream>>>(qhw, khw, vhw, attn_out, catw);

  // out[b][s][d] = cat @ Wo
  proj_kernel<2><<<pg, 256, 0, stream>>>(catw, WoT, out, (long)SS * DM, AD, DM, 1);
}

// Round 3
// 305.279 us; speedup vs baseline: 2.4704x; 2.2564x over previous
//
#include <hip/hip_runtime.h>
#include <hip/hip_bf16.h>

#define DM 1024
#define NH 16
#define AD 64
#define BB 2
#define SS 2048
#define LOG2E 1.44269504f

typedef float f32x4 __attribute__((ext_vector_type(4)));
typedef short bf16x8 __attribute__((ext_vector_type(8)));
typedef unsigned short u16;
typedef unsigned int u32;
typedef u16 u16x4 __attribute__((ext_vector_type(4)));
typedef u16 u16x8 __attribute__((ext_vector_type(8)));
typedef u32 u32x4 __attribute__((ext_vector_type(4)));

static __device__ __forceinline__ u16 f2bf(float f) {
  unsigned u = __builtin_bit_cast(unsigned, f);
  u += 0x7fffu + ((u >> 16) & 1u);  // round-to-nearest-even
  return (u16)(u >> 16);
}

#define MFMA16(a, b, c) __builtin_amdgcn_mfma_f32_16x16x32_bf16((a), (b), (c), 0, 0, 0)

// async global->LDS, 16B per lane (LDS dest linear: base + 16*lane)
static __device__ __forceinline__ void ld_lds16(const void* g, void* l) {
  __builtin_amdgcn_global_load_lds((const __attribute__((address_space(1))) u32*)g,
                                   (__attribute__((address_space(3))) u32*)l, 16, 0, 0);
}

// swizzled b128 read of 16B piece P (0..7) from row of a [64][64] u16 tile staged
// with pre-swizzled source: LDS[row][p] holds global piece (p ^ (row&7)).
#define KFRAG(buf, row, P) (*(const bf16x8*)(&(buf)[(row) * 64 + ((((P) ^ ((row) & 7))) << 3)]))
// swizzled b64 read: quad P (0..7), 8-byte half hh (0/1)
#define V64(buf, row, P, hh) \
  (*(const u16x4*)(&(buf)[(row) * 64 + ((((P) ^ ((row) & 7))) << 3) + (hh) * 4]))

// ---------------- fp32 -> bf16 cast, 8 elems/thread ----------------
__global__ __launch_bounds__(256, 4) void cast_bf16_kernel(const float* __restrict__ src,
                                                           u16* __restrict__ dst, int n8) {
  int i = blockIdx.x * blockDim.x + threadIdx.x;
  int stride = gridDim.x * blockDim.x;
  for (; i < n8; i += stride) {
    const f32x4* p = (const f32x4*)src + 2 * (size_t)i;
    f32x4 a = p[0], b = p[1];
    u16x8 o;
    o[0] = f2bf(a[0]); o[1] = f2bf(a[1]); o[2] = f2bf(a[2]); o[3] = f2bf(a[3]);
    o[4] = f2bf(b[0]); o[5] = f2bf(b[1]); o[6] = f2bf(b[2]); o[7] = f2bf(b[3]);
    *((u16x8*)dst + i) = o;
  }
}

// ---------------- LDS-tiled transpose+cast: src[R][C] f32 -> dst[C][R] bf16 ----------------
__global__ __launch_bounds__(256, 4) void tcast_kernel(const float* __restrict__ src,
                                                       u16* __restrict__ dst, int R, int C,
                                                       float scale) {
  __shared__ float T[64][65];
  long bo = (long)blockIdx.z * R * C;
  int r0 = blockIdx.x * 64, c0 = blockIdx.y * 64;
  int cl = threadIdx.x & 63, rl = threadIdx.x >> 6;
#pragma unroll
  for (int i = 0; i < 16; i++) {
    int rr = rl + 4 * i;
    T[cl][rr] = src[bo + (long)(r0 + rr) * C + c0 + cl];
  }
  __syncthreads();
#pragma unroll
  for (int i = 0; i < 16; i++) {
    int cc = rl + 4 * i;
    dst[bo + (long)(c0 + cc) * R + r0 + cl] = f2bf(T[cc][cl] * scale);
  }
}

// ---------------- projection GEMM with LDS double-buffered staging ----------------
// C[s,e] = sum_k X[b][s][k] * WT[col=h*64+e][k]; tile 64s x 64col, K-chunks of 64.
// block 256 (4 waves); wave w = 16-col slice. MODE 0: bf16 [s][e]; 1: bf16 [e][s]; 2: f32 [s][e].
template <int MODE>
__global__ __launch_bounds__(256, 5) void proj_kernel(const u16* __restrict__ X,
                                                      const u16* __restrict__ WT,
                                                      void* __restrict__ outp, long ob, long oh,
                                                      long os, long oe) {
  __shared__ u16 Ab[2][64 * 64];
  __shared__ u16 Bb[2][64 * 64];
  int s0 = blockIdx.x * 64, h = blockIdx.y, b = blockIdx.z;
  int tid = threadIdx.x, w = tid >> 6, lane = tid & 63, g = lane >> 4, li = lane & 15;
  const u16* xb = X + ((long)b * SS + s0) * DM;
  const u16* wb = WT + (long)h * 64 * DM;
  // staging map: 8KB tile = 512 16B-chunks; thread covers cc=tid and cc=tid+256
  int r1 = tid >> 3, p1 = (tid ^ (r1 & 7)) & 7;
  int r2 = (tid + 256) >> 3, p2 = ((tid + 256) ^ (r2 & 7)) & 7;
  const u16* as1 = xb + (long)r1 * DM + p1 * 8;
  const u16* as2 = xb + (long)r2 * DM + p2 * 8;
  const u16* bs1 = wb + (long)r1 * DM + p1 * 8;
  const u16* bs2 = wb + (long)r2 * DM + p2 * 8;
  u16* ad0 = &Ab[0][tid * 8]; u16* ad0b = &Ab[0][(tid + 256) * 8];
  u16* ad1 = &Ab[1][tid * 8]; u16* ad1b = &Ab[1][(tid + 256) * 8];
  u16* bd0 = &Bb[0][tid * 8]; u16* bd0b = &Bb[0][(tid + 256) * 8];
  u16* bd1 = &Bb[1][tid * 8]; u16* bd1b = &Bb[1][(tid + 256) * 8];

  ld_lds16(as1, ad0); ld_lds16(as2, ad0b);
  ld_lds16(bs1, bd0); ld_lds16(bs2, bd0b);
  asm volatile("s_waitcnt vmcnt(0)" ::: "memory");
  __syncthreads();

  f32x4 acc[4] = {};
  for (int kc = 0; kc < DM / 64; kc++) {
    if (kc + 1 < DM / 64) {
      int ko = (kc + 1) * 64;
      if (kc & 1) {
        ld_lds16(as1 + ko, ad0); ld_lds16(as2 + ko, ad0b);
        ld_lds16(bs1 + ko, bd0); ld_lds16(bs2 + ko, bd0b);
      } else {
        ld_lds16(as1 + ko, ad1); ld_lds16(as2 + ko, ad1b);
        ld_lds16(bs1 + ko, bd1); ld_lds16(bs2 + ko, bd1b);
      }
    }
    const u16* ab = Ab[kc & 1];
    const u16* bbuf = Bb[kc & 1];
    bf16x8 bf0 = KFRAG(bbuf, w * 16 + li, g);
    bf16x8 bf1 = KFRAG(bbuf, w * 16 + li, 4 + g);
#pragma unroll
    for (int mi = 0; mi < 4; mi++) {
      bf16x8 a0 = KFRAG(ab, mi * 16 + li, g);
      bf16x8 a1 = KFRAG(ab, mi * 16 + li, 4 + g);
      acc[mi] = MFMA16(a0, bf0, acc[mi]);
      acc[mi] = MFMA16(a1, bf1, acc[mi]);
    }
    asm volatile("s_waitcnt vmcnt(0)" ::: "memory");
    __syncthreads();
  }

  int e = w * 16 + li;
  long bh = (long)b * ob + (long)h * oh;
#pragma unroll
  for (int mi = 0; mi < 4; mi++) {
    int sb = s0 + mi * 16 + 4 * g;  // D row = (lane>>4)*4 + reg
    if (MODE == 0) {
      u16* o = (u16*)outp;
#pragma unroll
      for (int r = 0; r < 4; r++) o[bh + (long)(sb + r) * os + (long)e * oe] = f2bf(acc[mi][r]);
    } else if (MODE == 1) {
      u16x4 v;
#pragma unroll
      for (int r = 0; r < 4; r++) v[r] = f2bf(acc[mi][r]);
      *(u16x4*)((u16*)outp + bh + (long)e * oe + sb) = v;
    } else {
      float* o = (float*)outp;
#pragma unroll
      for (int r = 0; r < 4; r++) o[bh + (long)(sb + r) * os + (long)e * oe] = acc[mi][r];
    }
  }
}

// ---------------- fused attention, two-pass staged ----------------
// block = 512 thr (8 waves), q-tile 128 (16 q/wave), each wave sees ALL 2048 k.
// Pass 1: stage K chunks (64k x 64e) in LDS dbuf, S^T = K.Q^T per chunk, online (m,l).
// Pass 2: restage K (+V^T chunks), recompute S (bit-identical), write normalized attn f32,
//         PV via k-permuted A-frag (lane's own 8 p-values) + permuted V^T LDS reads.
__global__ __launch_bounds__(512, 4) void attn_kernel(const u16* __restrict__ qh,
                                                      const u16* __restrict__ kh,
                                                      const u16* __restrict__ vhT,
                                                      float* __restrict__ attn_out,
                                                      u16* __restrict__ cat) {
  __shared__ u16 Kb[2][64 * 64];
  __shared__ u16 Vb[2][64 * 64];
  int h = blockIdx.y, b = blockIdx.z;
  int hb = h * BB + b;
  int tid = threadIdx.x;
  int w = tid >> 6, lane = tid & 63;
  int g = lane >> 4, li = lane & 15;
  long base = (long)hb * SS * AD;
  const u16* qhb = qh + base;
  const u16* khb = kh + base;
  const u16* vhb = vhT + base;
  int q0 = blockIdx.x * 128 + w * 16;

  // Q fragments (B-operand): lane(g,li) = Q^T[e=8g..][q=li]
  bf16x8 bq0 = *(const bf16x8*)(qhb + (q0 + li) * AD + 8 * g);
  bf16x8 bq1 = *(const bf16x8*)(qhb + (q0 + li) * AD + 32 + 8 * g);

  // staging map: 8KB = 512 chunks, thread tid <-> chunk tid
  int srow = tid >> 3, spiece = (tid ^ (srow & 7)) & 7;
  const u16* ksrc = khb + (long)srow * AD + spiece * 8;       // K rows contiguous per chunk
  const u16* vsrc = vhb + (long)srow * SS + spiece * 8;       // V^T rows stride SS
  u16* kd0 = &Kb[0][tid * 8]; u16* kd1 = &Kb[1][tid * 8];
  u16* vd0 = &Vb[0][tid * 8]; u16* vd1 = &Vb[1][tid * 8];

  // ================= pass 1: online (m, l) =================
  float m_run = -3.0e38f, l_run = 0.f;
  ld_lds16(ksrc, kd0);
  asm volatile("s_waitcnt vmcnt(0)" ::: "memory");
  __syncthreads();
  for (int ch = 0; ch < SS / 64; ch++) {
    if (ch + 1 < SS / 64) ld_lds16(ksrc + (ch + 1) * 64 * AD, (ch & 1) ? kd0 : kd1);
    const u16* kb = Kb[ch & 1];
    f32x4 sacc[4] = {};
#pragma unroll
    for (int mi = 0; mi < 4; mi++) {
      bf16x8 a0 = KFRAG(kb, mi * 16 + li, g);
      bf16x8 a1 = KFRAG(kb, mi * 16 + li, 4 + g);
      sacc[mi] = MFMA16(a0, bq0, sacc[mi]);
      sacc[mi] = MFMA16(a1, bq1, sacc[mi]);
    }
    float cm = m_run;
#pragma unroll
    for (int c = 0; c < 4; c++)
#pragma unroll
      for (int r = 0; r < 4; r++) cm = fmaxf(cm, sacc[c][r]);
    l_run *= exp2f((m_run - cm) * LOG2E);
#pragma unroll
    for (int c = 0; c < 4; c++)
#pragma unroll
      for (int r = 0; r < 4; r++) l_run += exp2f((sacc[c][r] - cm) * LOG2E);
    m_run = cm;
    asm volatile("s_waitcnt vmcnt(0)" ::: "memory");
    __syncthreads();
  }
  // merge (m,l) across the 4 g-lanes holding the same q=li
#pragma unroll
  for (int d = 16; d <= 32; d <<= 1) {
    float om = __shfl_xor(m_run, d);
    float ol = __shfl_xor(l_run, d);
    float nm = fmaxf(m_run, om);
    l_run = l_run * exp2f((m_run - nm) * LOG2E) + ol * exp2f((om - nm) * LOG2E);
    m_run = nm;
  }
  float rinv = 1.0f / l_run;
  float mC = m_run * LOG2E;

  // ================= pass 2: attn write + PV =================
  ld_lds16(ksrc, kd0);
  ld_lds16(vsrc, vd0);
  asm volatile("s_waitcnt vmcnt(0)" ::: "memory");
  __syncthreads();
  f32x4 accv[4] = {};
  float* arow = attn_out + ((long)hb * SS + q0 + li) * SS;
  for (int ch = 0; ch < SS / 64; ch++) {
    if (ch + 1 < SS / 64) {
      ld_lds16(ksrc + (ch + 1) * 64 * AD, (ch & 1) ? kd0 : kd1);
      ld_lds16(vsrc + (ch + 1) * 64, (ch & 1) ? vd0 : vd1);
    }
    const u16* kb = Kb[ch & 1];
    const u16* vb = Vb[ch & 1];
    f32x4 sacc[4] = {};
#pragma unroll
    for (int mi = 0; mi < 4; mi++) {
      bf16x8 a0 = KFRAG(kb, mi * 16 + li, g);
      bf16x8 a1 = KFRAG(kb, mi * 16 + li, 4 + g);
      sacc[mi] = MFMA16(a0, bq0, sacc[mi]);
      sacc[mi] = MFMA16(a1, bq1, sacc[mi]);
    }
    // p = exp2(s*log2e - m*log2e) * rinv : write attn f32, pack bf16 for PV
    u32 pw[8];
#pragma unroll
    for (int c = 0; c < 4; c++) {
      f32x4 pv;
#pragma unroll
      for (int r = 0; r < 4; r++) pv[r] = exp2f(sacc[c][r] * LOG2E - mC) * rinv;
      *(f32x4*)(arow + ch * 64 + c * 16 + 4 * g) = pv;
      pw[2 * c] = (u32)f2bf(pv[0]) | ((u32)f2bf(pv[1]) << 16);
      pw[2 * c + 1] = (u32)f2bf(pv[2]) | ((u32)f2bf(pv[3]) << 16);
    }
    // PV: k-step kk covers lane's own k = {32kk+16cc+4g+r}; A-frag = own packed p.
#pragma unroll
    for (int kk = 0; kk < 2; kk++) {
      u32x4 aw = {pw[4 * kk], pw[4 * kk + 1], pw[4 * kk + 2], pw[4 * kk + 3]};
      bf16x8 ap = __builtin_bit_cast(bf16x8, aw);
#pragma unroll
      for (int et = 0; et < 4; et++) {
        int row = et * 16 + li;  // e-row of V^T tile
        u16x4 b0 = V64(vb, row, 4 * kk + (g >> 1), g & 1);      // cc=0 piece
        u16x4 b1 = V64(vb, row, 4 * kk + 2 + (g >> 1), g & 1);  // cc=1 piece
        u16x8 ub = {b0[0], b0[1], b0[2], b0[3], b1[0], b1[1], b1[2], b1[3]};
        bf16x8 bv = __builtin_bit_cast(bf16x8, ub);
        accv[et] = MFMA16(ap, bv, accv[et]);
      }
    }
    asm volatile("s_waitcnt vmcnt(0)" ::: "memory");
    __syncthreads();
  }

  // epilogue: att already normalized; lane(g,li) holds att[q=4g+r][e=et*16+li]
#pragma unroll
  for (int et = 0; et < 4; et++)
#pragma unroll
    for (int r = 0; r < 4; r++)
      cat[((long)b * SS + q0 + 4 * g + r) * DM + h * AD + et * 16 + li] = f2bf(accv[et][r]);
}

extern "C" void kernel_launch(void* const* d_in, const int* in_sizes, int n_in, void* d_out,
                              int out_size, void* d_ws, size_t ws_size, hipStream_t stream) {
  const float* q = (const float*)d_in[0];
  const float* k = (const float*)d_in[1];
  const float* v = (const float*)d_in[2];
  const float* Wq = (const float*)d_in[3];
  const float* Wk = (const float*)d_in[4];
  const float* Wv = (const float*)d_in[5];
  const float* Wo = (const float*)d_in[6];
  float* out = (float*)d_out;
  float* attn_out = out + (long)BB * SS * DM;

  const long NX = (long)BB * SS * DM;  // 4,194,304
  const long NW = (long)NH * DM * AD;  // 1,048,576
  u16* ws = (u16*)d_ws;
  u16* xq = ws;
  u16* xk = xq + NX;
  u16* xv = xk + NX;
  u16* WqT = xv + NX;
  u16* WkT = WqT + NW;
  u16* WvT = WkT + NW;
  u16* WoT = WvT + NW;
  u16* qhw = WoT + (long)DM * DM;
  u16* khw = qhw + NX;
  u16* vhw = khw + NX;
  u16* catw = vhw + NX;  // total ws use: 64 MiB

  cast_bf16_kernel<<<2048, 256, 0, stream>>>(q, xq, (int)(NX / 8));
  cast_bf16_kernel<<<2048, 256, 0, stream>>>(k, xk, (int)(NX / 8));
  cast_bf16_kernel<<<2048, 256, 0, stream>>>(v, xv, (int)(NX / 8));
  // fold 1/ATT_DIM into WqT: exact (2^-6)
  tcast_kernel<<<dim3(16, 1, NH), 256, 0, stream>>>(Wq, WqT, DM, AD, 1.0f / AD);
  tcast_kernel<<<dim3(16, 1, NH), 256, 0, stream>>>(Wk, WkT, DM, AD, 1.0f);
  tcast_kernel<<<dim3(16, 1, NH), 256, 0, stream>>>(Wv, WvT, DM, AD, 1.0f);
  tcast_kernel<<<dim3(16, 16, 1), 256, 0, stream>>>(Wo, WoT, DM, DM, 1.0f);

  dim3 pg(SS / 64, NH, BB);
  // qh[h][b][s][e], kh[h][b][s][e]
  proj_kernel<0><<<pg, 256, 0, stream>>>(xq, WqT, qhw, (long)SS * AD, (long)BB * SS * AD, AD, 1);
  proj_kernel<0><<<pg, 256, 0, stream>>>(xk, WkT, khw, (long)SS * AD, (long)BB * SS * AD, AD, 1);
  // vhT[h][b][e][s]
  proj_kernel<1><<<pg, 256, 0, stream>>>(xv, WvT, vhw, (long)SS * AD, (long)BB * SS * AD, 1, SS);

  attn_kernel<<<dim3(SS / 128, NH, BB), 512, 0, stream>>>(qhw, khw, vhw, attn_out, catw);

  // out[b][s][d] = cat @ Wo
  proj_kernel<2><<<pg, 256, 0, stream>>>(catw, WoT, out, (long)SS * DM, AD, DM, 1);
}

// Round 4
// 282.033 us; speedup vs baseline: 2.6741x; 1.0824x over previous
//
#include <hip/hip_runtime.h>
#include <hip/hip_bf16.h>

#define DM 1024
#define NH 16
#define AD 64
#define BB 2
#define SS 2048
#define LOG2E 1.44269504f

typedef float f32x4 __attribute__((ext_vector_type(4)));
typedef short bf16x8 __attribute__((ext_vector_type(8)));
typedef unsigned short u16;
typedef unsigned int u32;
typedef u16 u16x4 __attribute__((ext_vector_type(4)));
typedef u16 u16x8 __attribute__((ext_vector_type(8)));
typedef u32 u32x4 __attribute__((ext_vector_type(4)));

static __device__ __forceinline__ u16 f2bf(float f) {
  unsigned u = __builtin_bit_cast(unsigned, f);
  u += 0x7fffu + ((u >> 16) & 1u);  // round-to-nearest-even
  return (u16)(u >> 16);
}

#define MFMA16(a, b, c) __builtin_amdgcn_mfma_f32_16x16x32_bf16((a), (b), (c), 0, 0, 0)

// async global->LDS, 16B per lane (LDS dest linear: base + 16*lane)
static __device__ __forceinline__ void ld_lds16(const void* g, void* l) {
  __builtin_amdgcn_global_load_lds((const __attribute__((address_space(1))) u32*)g,
                                   (__attribute__((address_space(3))) u32*)l, 16, 0, 0);
}

// counted waits + raw barrier (T3/T4: never drain stores/prefetch to 0 in-loop)
#define WAITV(N)                                             \
  do {                                                       \
    asm volatile("s_waitcnt vmcnt(" #N ")" ::: "memory");    \
    __builtin_amdgcn_sched_barrier(0);                       \
  } while (0)
#define WAITL0()                                             \
  do {                                                       \
    asm volatile("s_waitcnt lgkmcnt(0)" ::: "memory");       \
    __builtin_amdgcn_sched_barrier(0);                       \
  } while (0)
#define BAR() __builtin_amdgcn_s_barrier()

// swizzled b128 read of 16B piece P (0..7) from row of a [64][64] u16 tile staged
// with pre-swizzled source: LDS[row][p] holds global piece (p ^ (row&7)).
#define KFRAG(buf, row, P) (*(const bf16x8*)(&(buf)[(row) * 64 + ((((P) ^ ((row) & 7))) << 3)]))
// swizzled b64 read: quad P (0..7), 8-byte half hh (0/1)
#define V64(buf, row, P, hh) \
  (*(const u16x4*)(&(buf)[(row) * 64 + ((((P) ^ ((row) & 7))) << 3) + (hh) * 4]))

// ---------------- fp32 -> bf16 cast of q,k,v in one launch ----------------
__global__ __launch_bounds__(256, 4) void cast3_kernel(const float* __restrict__ s0,
                                                       const float* __restrict__ s1,
                                                       const float* __restrict__ s2,
                                                       u16* __restrict__ d0, u16* __restrict__ d1,
                                                       u16* __restrict__ d2, int n8) {
  const float* src = blockIdx.y == 0 ? s0 : blockIdx.y == 1 ? s1 : s2;
  u16* dst = blockIdx.y == 0 ? d0 : blockIdx.y == 1 ? d1 : d2;
  int i = blockIdx.x * blockDim.x + threadIdx.x;
  int stride = gridDim.x * blockDim.x;
  for (; i < n8; i += stride) {
    const f32x4* p = (const f32x4*)src + 2 * (size_t)i;
    f32x4 a = p[0], b = p[1];
    u16x8 o;
    o[0] = f2bf(a[0]); o[1] = f2bf(a[1]); o[2] = f2bf(a[2]); o[3] = f2bf(a[3]);
    o[4] = f2bf(b[0]); o[5] = f2bf(b[1]); o[6] = f2bf(b[2]); o[7] = f2bf(b[3]);
    *((u16x8*)dst + i) = o;
  }
}

// ---------------- LDS-tiled transpose+cast ----------------
// MODE 0: one src [z][R][C]; MODE 1: three srcs (Wq/Wk/Wv), z/16 selects, scale on z<16.
template <int MODE>
__global__ __launch_bounds__(256, 4) void tcast_kernel(const float* __restrict__ s0,
                                                       const float* __restrict__ s1,
                                                       const float* __restrict__ s2,
                                                       u16* __restrict__ dst, int R, int C,
                                                       float scale0) {
  __shared__ float T[64][65];
  const float* src;
  u16* dstp;
  float scale;
  long bo;
  if (MODE == 0) {
    src = s0; bo = (long)blockIdx.z * R * C; dstp = dst; scale = scale0;
  } else {
    int which = blockIdx.z >> 4, zz = blockIdx.z & 15;
    src = which == 0 ? s0 : which == 1 ? s1 : s2;
    bo = (long)zz * R * C;
    dstp = dst + (long)which * NH * R * C;
    scale = which == 0 ? scale0 : 1.0f;
  }
  int r0 = blockIdx.x * 64, c0 = blockIdx.y * 64;
  int cl = threadIdx.x & 63, rl = threadIdx.x >> 6;
#pragma unroll
  for (int i = 0; i < 16; i++) {
    int rr = rl + 4 * i;
    T[cl][rr] = src[bo + (long)(r0 + rr) * C + c0 + cl];
  }
  __syncthreads();
#pragma unroll
  for (int i = 0; i < 16; i++) {
    int cc = rl + 4 * i;
    dstp[bo + (long)(c0 + cc) * R + r0 + cl] = f2bf(T[cc][cl] * scale);
  }
}

// ---------------- projection GEMM with LDS double-buffered staging, counted waits ----------
// C[s,e] = sum_k X[b][s][k] * WT[col=h*64+e][k]; tile 64s x 64col, K-chunks of 64.
// block 256 (4 waves); wave w = 16-col slice. MODE 0: bf16 [s][e]; 1: bf16 [e][s]; 2: f32 [s][e].
template <int MODE>
__global__ __launch_bounds__(256, 5) void proj_kernel(const u16* __restrict__ X,
                                                      const u16* __restrict__ WT,
                                                      void* __restrict__ outp, long ob, long oh,
                                                      long os, long oe) {
  __shared__ u16 Ab[2][64 * 64];
  __shared__ u16 Bb[2][64 * 64];
  int s0 = blockIdx.x * 64, h = blockIdx.y, b = blockIdx.z;
  int tid = threadIdx.x, w = tid >> 6, lane = tid & 63, g = lane >> 4, li = lane & 15;
  const u16* xb = X + ((long)b * SS + s0) * DM;
  const u16* wb = WT + (long)h * 64 * DM;
  // staging map: 8KB tile = 512 16B-chunks; thread covers cc=tid and cc=tid+256
  int r1 = tid >> 3, p1 = (tid ^ (r1 & 7)) & 7;
  int r2 = (tid + 256) >> 3, p2 = ((tid + 256) ^ (r2 & 7)) & 7;
  const u16* as1 = xb + (long)r1 * DM + p1 * 8;
  const u16* as2 = xb + (long)r2 * DM + p2 * 8;
  const u16* bs1 = wb + (long)r1 * DM + p1 * 8;
  const u16* bs2 = wb + (long)r2 * DM + p2 * 8;
  u16* ad0 = &Ab[0][tid * 8]; u16* ad0b = &Ab[0][(tid + 256) * 8];
  u16* ad1 = &Ab[1][tid * 8]; u16* ad1b = &Ab[1][(tid + 256) * 8];
  u16* bd0 = &Bb[0][tid * 8]; u16* bd0b = &Bb[0][(tid + 256) * 8];
  u16* bd1 = &Bb[1][tid * 8]; u16* bd1b = &Bb[1][(tid + 256) * 8];

  ld_lds16(as1, ad0); ld_lds16(as2, ad0b);
  ld_lds16(bs1, bd0); ld_lds16(bs2, bd0b);

  f32x4 acc[4] = {};
  for (int kc = 0; kc < DM / 64; kc++) {
    if (kc + 1 < DM / 64) {
      int ko = (kc + 1) * 64;
      if (kc & 1) {
        ld_lds16(as1 + ko, ad0); ld_lds16(as2 + ko, ad0b);
        ld_lds16(bs1 + ko, bd0); ld_lds16(bs2 + ko, bd0b);
      } else {
        ld_lds16(as1 + ko, ad1); ld_lds16(as2 + ko, ad1b);
        ld_lds16(bs1 + ko, bd1); ld_lds16(bs2 + ko, bd1b);
      }
      WAITV(4);  // wait only previous chunk's 4 loads (oldest); 4 in flight
    } else {
      WAITV(0);
    }
    BAR();
    const u16* ab = Ab[kc & 1];
    const u16* bbuf = Bb[kc & 1];
    bf16x8 bf0 = KFRAG(bbuf, w * 16 + li, g);
    bf16x8 bf1 = KFRAG(bbuf, w * 16 + li, 4 + g);
#pragma unroll
    for (int mi = 0; mi < 4; mi++) {
      bf16x8 a0 = KFRAG(ab, mi * 16 + li, g);
      bf16x8 a1 = KFRAG(ab, mi * 16 + li, 4 + g);
      acc[mi] = MFMA16(a0, bf0, acc[mi]);
      acc[mi] = MFMA16(a1, bf1, acc[mi]);
    }
    WAITL0();
    BAR();
  }

  int e = w * 16 + li;
  long bh = (long)b * ob + (long)h * oh;
#pragma unroll
  for (int mi = 0; mi < 4; mi++) {
    int sb = s0 + mi * 16 + 4 * g;  // D row = (lane>>4)*4 + reg
    if (MODE == 0) {
      u16* o = (u16*)outp;
#pragma unroll
      for (int r = 0; r < 4; r++) o[bh + (long)(sb + r) * os + (long)e * oe] = f2bf(acc[mi][r]);
    } else if (MODE == 1) {
      u16x4 v;
#pragma unroll
      for (int r = 0; r < 4; r++) v[r] = f2bf(acc[mi][r]);
      *(u16x4*)((u16*)outp + bh + (long)e * oe + sb) = v;
    } else {
      float* o = (float*)outp;
#pragma unroll
      for (int r = 0; r < 4; r++) o[bh + (long)(sb + r) * os + (long)e * oe] = acc[mi][r];
    }
  }
}

// ---------------- fused attention, two-pass staged, counted waits ----------------
// block = 512 thr (8 waves), q-tile 128 (16 q/wave), each wave sees ALL 2048 k.
// Pass 1: stage K chunks (64k x 64e) in LDS dbuf, S^T = K.Q^T per chunk, online (m,l).
// Pass 2: restage K (+V^T chunks), recompute S (bit-identical), write normalized attn f32
//         (stores NEVER drained in-loop), PV via k-permuted A-frag + permuted V^T reads.
__global__ __launch_bounds__(512, 4) void attn_kernel(const u16* __restrict__ qh,
                                                      const u16* __restrict__ kh,
                                                      const u16* __restrict__ vhT,
                                                      float* __restrict__ attn_out,
                                                      u16* __restrict__ cat) {
  __shared__ u16 Kb[2][64 * 64];
  __shared__ u16 Vb[2][64 * 64];
  int h = blockIdx.y, b = blockIdx.z;
  int hb = h * BB + b;
  int tid = threadIdx.x;
  int w = tid >> 6, lane = tid & 63;
  int g = lane >> 4, li = lane & 15;
  long base = (long)hb * SS * AD;
  const u16* qhb = qh + base;
  const u16* khb = kh + base;
  const u16* vhb = vhT + base;
  int q0 = blockIdx.x * 128 + w * 16;

  // Q fragments (B-operand): lane(g,li) = Q^T[e=8g..][q=li]
  bf16x8 bq0 = *(const bf16x8*)(qhb + (q0 + li) * AD + 8 * g);
  bf16x8 bq1 = *(const bf16x8*)(qhb + (q0 + li) * AD + 32 + 8 * g);

  // staging map: 8KB = 512 chunks, thread tid <-> chunk tid
  int srow = tid >> 3, spiece = (tid ^ (srow & 7)) & 7;
  const u16* ksrc = khb + (long)srow * AD + spiece * 8;  // K rows contiguous per chunk
  const u16* vsrc = vhb + (long)srow * SS + spiece * 8;  // V^T rows stride SS
  u16* kd0 = &Kb[0][tid * 8]; u16* kd1 = &Kb[1][tid * 8];
  u16* vd0 = &Vb[0][tid * 8]; u16* vd1 = &Vb[1][tid * 8];

  // ================= pass 1: online (m, l) =================
  float m_run = -3.0e38f, l_run = 0.f;
  ld_lds16(ksrc, kd0);
  for (int ch = 0; ch < SS / 64; ch++) {
    if (ch + 1 < SS / 64) {
      ld_lds16(ksrc + (ch + 1) * 64 * AD, (ch & 1) ? kd0 : kd1);
      WAITV(1);  // oldest (this chunk's load) done; 1 in flight
    } else {
      WAITV(0);
    }
    BAR();
    const u16* kb = Kb[ch & 1];
    f32x4 sacc[4] = {};
#pragma unroll
    for (int mi = 0; mi < 4; mi++) {
      bf16x8 a0 = KFRAG(kb, mi * 16 + li, g);
      bf16x8 a1 = KFRAG(kb, mi * 16 + li, 4 + g);
      sacc[mi] = MFMA16(a0, bq0, sacc[mi]);
      sacc[mi] = MFMA16(a1, bq1, sacc[mi]);
    }
    float cm = m_run;
#pragma unroll
    for (int c = 0; c < 4; c++)
#pragma unroll
      for (int r = 0; r < 4; r++) cm = fmaxf(cm, sacc[c][r]);
    l_run *= exp2f((m_run - cm) * LOG2E);
#pragma unroll
    for (int c = 0; c < 4; c++)
#pragma unroll
      for (int r = 0; r < 4; r++) l_run += exp2f((sacc[c][r] - cm) * LOG2E);
    m_run = cm;
    WAITL0();
    BAR();
  }
  // merge (m,l) across the 4 g-lanes holding the same q=li
#pragma unroll
  for (int d = 16; d <= 32; d <<= 1) {
    float om = __shfl_xor(m_run, d);
    float ol = __shfl_xor(l_run, d);
    float nm = fmaxf(m_run, om);
    l_run = l_run * exp2f((m_run - nm) * LOG2E) + ol * exp2f((om - nm) * LOG2E);
    m_run = nm;
  }
  // p = exp2(s*log2e - moff) is already normalized
  float moff = m_run * LOG2E + log2f(l_run);

  // ================= pass 2: attn write + PV =================
  ld_lds16(ksrc, kd0);
  ld_lds16(vsrc, vd0);
  f32x4 accv[4] = {};
  float* arow = attn_out + ((long)hb * SS + q0 + li) * SS;
  for (int ch = 0; ch < SS / 64; ch++) {
    if (ch + 1 < SS / 64) {
      ld_lds16(ksrc + (ch + 1) * 64 * AD, (ch & 1) ? kd0 : kd1);
      ld_lds16(vsrc + (ch + 1) * 64, (ch & 1) ? vd0 : vd1);
      if (ch == 0) {
        WAITV(2);  // queue: [K0,V0,K1,V1] -> K0,V0 done
      } else {
        WAITV(6);  // queue: [Kc,Vc, S_{c-1}(4), Kn,Vn] -> Kc,Vc done; stores fly
      }
    } else {
      WAITV(4);  // queue: [Kc,Vc, S_{c-1}(4)] -> Kc,Vc done
    }
    BAR();
    const u16* kb = Kb[ch & 1];
    const u16* vb = Vb[ch & 1];
    f32x4 sacc[4] = {};
#pragma unroll
    for (int mi = 0; mi < 4; mi++) {
      bf16x8 a0 = KFRAG(kb, mi * 16 + li, g);
      bf16x8 a1 = KFRAG(kb, mi * 16 + li, 4 + g);
      sacc[mi] = MFMA16(a0, bq0, sacc[mi]);
      sacc[mi] = MFMA16(a1, bq1, sacc[mi]);
    }
    // p = exp2(s*log2e - moff): write attn f32, pack bf16 for PV
    u32 pw[8];
#pragma unroll
    for (int c = 0; c < 4; c++) {
      f32x4 pv;
#pragma unroll
      for (int r = 0; r < 4; r++) pv[r] = exp2f(sacc[c][r] * LOG2E - moff);
      *(f32x4*)(arow + ch * 64 + c * 16 + 4 * g) = pv;
      pw[2 * c] = (u32)f2bf(pv[0]) | ((u32)f2bf(pv[1]) << 16);
      pw[2 * c + 1] = (u32)f2bf(pv[2]) | ((u32)f2bf(pv[3]) << 16);
    }
    // PV: k-step kk covers lane's own k = {32kk+16cc+4g+r}; A-frag = own packed p.
#pragma unroll
    for (int kk = 0; kk < 2; kk++) {
      u32x4 aw = {pw[4 * kk], pw[4 * kk + 1], pw[4 * kk + 2], pw[4 * kk + 3]};
      bf16x8 ap = __builtin_bit_cast(bf16x8, aw);
#pragma unroll
      for (int et = 0; et < 4; et++) {
        int row = et * 16 + li;  // e-row of V^T tile
        u16x4 b0 = V64(vb, row, 4 * kk + (g >> 1), g & 1);      // cc=0 piece
        u16x4 b1 = V64(vb, row, 4 * kk + 2 + (g >> 1), g & 1);  // cc=1 piece
        u16x8 ub = {b0[0], b0[1], b0[2], b0[3], b1[0], b1[1], b1[2], b1[3]};
        bf16x8 bv = __builtin_bit_cast(bf16x8, ub);
        accv[et] = MFMA16(ap, bv, accv[et]);
      }
    }
    WAITL0();
    BAR();
  }

  // epilogue: att already normalized; lane(g,li) holds att[q=4g+r][e=et*16+li]
#pragma unroll
  for (int et = 0; et < 4; et++)
#pragma unroll
    for (int r = 0; r < 4; r++)
      cat[((long)b * SS + q0 + 4 * g + r) * DM + h * AD + et * 16 + li] = f2bf(accv[et][r]);
}

extern "C" void kernel_launch(void* const* d_in, const int* in_sizes, int n_in, void* d_out,
                              int out_size, void* d_ws, size_t ws_size, hipStream_t stream) {
  const float* q = (const float*)d_in[0];
  const float* k = (const float*)d_in[1];
  const float* v = (const float*)d_in[2];
  const float* Wq = (const float*)d_in[3];
  const float* Wk = (const float*)d_in[4];
  const float* Wv = (const float*)d_in[5];
  const float* Wo = (const float*)d_in[6];
  float* out = (float*)d_out;
  float* attn_out = out + (long)BB * SS * DM;

  const long NX = (long)BB * SS * DM;  // 4,194,304
  const long NW = (long)NH * DM * AD;  // 1,048,576
  u16* ws = (u16*)d_ws;
  u16* xq = ws;
  u16* xk = xq + NX;
  u16* xv = xk + NX;
  u16* WqT = xv + NX;  // WqT, WkT, WvT contiguous (tcast MODE 1 relies on this)
  u16* WkT = WqT + NW;
  u16* WvT = WkT + NW;
  u16* WoT = WvT + NW;
  u16* qhw = WoT + (long)DM * DM;
  u16* khw = qhw + NX;
  u16* vhw = khw + NX;
  u16* catw = vhw + NX;  // total ws use: 64 MiB

  cast3_kernel<<<dim3(700, 3), 256, 0, stream>>>(q, k, v, xq, xk, xv, (int)(NX / 8));
  // fold 1/ATT_DIM into WqT: exact (2^-6)
  tcast_kernel<1><<<dim3(16, 1, 48), 256, 0, stream>>>(Wq, Wk, Wv, WqT, DM, AD, 1.0f / AD);
  tcast_kernel<0><<<dim3(16, 16, 1), 256, 0, stream>>>(Wo, nullptr, nullptr, WoT, DM, DM, 1.0f);

  dim3 pg(SS / 64, NH, BB);
  // qh[h][b][s][e], kh[h][b][s][e]
  proj_kernel<0><<<pg, 256, 0, stream>>>(xq, WqT, qhw, (long)SS * AD, (long)BB * SS * AD, AD, 1);
  proj_kernel<0><<<pg, 256, 0, stream>>>(xk, WkT, khw, (long)SS * AD, (long)BB * SS * AD, AD, 1);
  // vhT[h][b][e][s]
  proj_kernel<1><<<pg, 256, 0, stream>>>(xv, WvT, vhw, (long)SS * AD, (long)BB * SS * AD, 1, SS);

  attn_kernel<<<dim3(SS / 128, NH, BB), 512, 0, stream>>>(qhw, khw, vhw, attn_out, catw);

  // out[b][s][d] = cat @ Wo
  proj_kernel<2><<<pg, 256, 0, stream>>>(catw, WoT, out, (long)SS * DM, AD, DM, 1);
}